// Round 14
// baseline (494.923 us; speedup 1.0000x reference)
//
#include <hip/hip_runtime.h>

#define NN 50000
#define MP 50048        // 782*64 padded rows
#define EE 800000
#define KK 2304         // G cols = (R+1)*256; cols [2048,2304) = self features

typedef __attribute__((ext_vector_type(8))) short short8;
typedef __attribute__((ext_vector_type(4))) float f32x4;

__device__ __forceinline__ float bf2f(unsigned short u) {
  unsigned int x = ((unsigned int)u) << 16;
  float f; __builtin_memcpy(&f, &x, 4); return f;
}
__device__ __forceinline__ unsigned short f2bf(float f) {
  unsigned int x; __builtin_memcpy(&x, &f, 4);
  return (unsigned short)((x + 0x7fffu + ((x >> 16) & 1u)) >> 16);
}

// ws layout (bytes), 16B-aligned
constexpr size_t OFF_XB   = 0;                 // NN*256*2   = 25,600,000
constexpr size_t OFF_WT   = 25600000;          // 256*2304*2 =  1,179,648
constexpr size_t OFF_G    = 26779648;          // MP*2304*2  = 230,621,184 -> end 257,400,832
constexpr size_t OFF_CNT2 = 257400832;         // NN*8*4     =  1,600,000
constexpr size_t OFF_OFFS = 259000832;         // (NN+1)*4 (padded to 200,016)
constexpr size_t OFF_SUB  = 259200848;         // (NN*8+1)*4 (padded to 1,600,016)
constexpr size_t OFF_EIX  = 260800864;         // EE*4 -> total ~264.0MB

// ---- build B^T bf16 [256 out-cols][2304 K]: Bt[o][r*256+i] = W_r[i][o]; cols 2048+: loop[i][o]
__global__ __launch_bounds__(256) void build_w_kernel(
    const float* __restrict__ bases, const float* __restrict__ comp,
    const float* __restrict__ loopw, unsigned short* __restrict__ Bt) {
  int kg = blockIdx.x * 256 + threadIdx.x;   // 0..2303 (gridDim.x = 9)
  int o  = blockIdx.y;                       // 0..255
  float v;
  if (kg < 2048) {
    int r = kg >> 8, i = kg & 255;
    v = 0.f;
#pragma unroll
    for (int b = 0; b < 4; ++b)
      v += comp[r * 4 + b] * bases[((size_t)b * 256 + i) * 256 + o];
  } else {
    v = loopw[(kg & 255) * 256 + o];
  }
  Bt[(size_t)o * KK + kg] = f2bf(v);
}

// ---- convert X fp32 -> bf16 (NN rows)
__global__ __launch_bounds__(256) void convert_x_kernel(
    const float* __restrict__ X, unsigned short* __restrict__ Xb) {
  size_t e0 = ((size_t)blockIdx.x * 256 + threadIdx.x) * 4;
  float4 v = *(const float4*)(X + e0);
  ushort4 o;
  o.x = f2bf(v.x); o.y = f2bf(v.y); o.z = f2bf(v.z); o.w = f2bf(v.w);
  *(ushort4*)(Xb + e0) = o;
}

// ---- CSR over (dst, rel) buckets
__global__ __launch_bounds__(256) void count_kernel(const int* __restrict__ dst,
                                                    const int* __restrict__ etype,
                                                    int* __restrict__ cnt2) {
  int e = blockIdx.x * 256 + threadIdx.x;
  if (e < EE) atomicAdd(&cnt2[dst[e] * 8 + etype[e]], 1);
}

// node-level exclusive scan
__global__ __launch_bounds__(1024) void scan_kernel(const int* __restrict__ cnt2,
                                                    int* __restrict__ offsets) {
  __shared__ int wsum[16];
  __shared__ int carry_s;
  int tid = threadIdx.x, lane = tid & 63, wid = tid >> 6;
  if (tid == 0) carry_s = 0;
  __syncthreads();
  for (int base = 0; base < NN; base += 1024) {
    int i = base + tid;
    int v = 0;
    if (i < NN) {
      int4 c0 = *(const int4*)(cnt2 + (size_t)i * 8);
      int4 c1 = *(const int4*)(cnt2 + (size_t)i * 8 + 4);
      v = c0.x + c0.y + c0.z + c0.w + c1.x + c1.y + c1.z + c1.w;
    }
    int incl = v;
#pragma unroll
    for (int d = 1; d < 64; d <<= 1) {
      int t = __shfl_up(incl, d, 64);
      if (lane >= d) incl += t;
    }
    if (lane == 63) wsum[wid] = incl;
    __syncthreads();
    int wpre = 0;
    for (int w = 0; w < wid; ++w) wpre += wsum[w];
    if (i < NN) offsets[i] = carry_s + wpre + incl - v;
    __syncthreads();
    if (tid == 1023) carry_s += wpre + incl;
    __syncthreads();
  }
  if (threadIdx.x == 0) offsets[NN] = carry_s;
}

// expand node offsets to per-(d,r) segment starts
__global__ __launch_bounds__(256) void suboff_kernel(const int* __restrict__ cnt2,
                                                     const int* __restrict__ offsets,
                                                     int* __restrict__ sub) {
  int d = blockIdx.x * 256 + threadIdx.x;
  if (d >= NN) return;
  int run = offsets[d];
  int4 c0 = *(const int4*)(cnt2 + (size_t)d * 8);
  int4 c1 = *(const int4*)(cnt2 + (size_t)d * 8 + 4);
  int4 s0, s1;
  s0.x = run; run += c0.x;
  s0.y = run; run += c0.y;
  s0.z = run; run += c0.z;
  s0.w = run; run += c0.w;
  s1.x = run; run += c1.x;
  s1.y = run; run += c1.y;
  s1.z = run; run += c1.z;
  s1.w = run; run += c1.w;
  *(int4*)(sub + (size_t)d * 8)     = s0;
  *(int4*)(sub + (size_t)d * 8 + 4) = s1;
  if (d == NN - 1) sub[NN * 8] = run;   // == EE
}

// scatter src ids; cnt2 doubles as a decrementing cursor
__global__ __launch_bounds__(256) void scatter_kernel(
    const int* __restrict__ src, const int* __restrict__ dst,
    const int* __restrict__ etype, const int* __restrict__ sub,
    int* __restrict__ cnt2, int* __restrict__ eidx) {
  int e = blockIdx.x * 256 + threadIdx.x;
  if (e < EE) {
    int b = dst[e] * 8 + etype[e];
    int pos = atomicAdd(&cnt2[b], -1) - 1;
    eidx[sub[b] + pos] = src[e];
  }
}

// ---- gather-sum: G[d][r*256+i] = sum_{e in seg(d,r)} x[src][i]; G[d][2048+i] = x[d][i]
// TWO waves per node (half=0: r0..3, half=1: r4..7 + self) -> shorter serial chains, 2x MLP
__global__ __launch_bounds__(256) void gather_kernel(
    const unsigned short* __restrict__ Xb, const int* __restrict__ sub,
    const int* __restrict__ eidx, unsigned short* __restrict__ G) {
  int wid = threadIdx.x >> 6, lane = threadIdx.x & 63;
  int d = blockIdx.x * 2 + (wid >> 1);     // grid 25024*2 = 50048 = MP
  int half = wid & 1;
  int o4 = lane * 4;
  unsigned short* gp = G + (size_t)d * KK + o4;
  if (d >= NN) {                           // zero pad rows (GEMM-safe)
    ushort4 z = {0, 0, 0, 0};
    if (half == 0) {
#pragma unroll
      for (int r = 0; r < 4; ++r) *(ushort4*)(gp + r * 256) = z;
    } else {
#pragma unroll
      for (int r = 4; r < 9; ++r) *(ushort4*)(gp + r * 256) = z;
    }
    return;
  }
  const int b0 = d * 8 + half * 4;
  int bnd[5];
#pragma unroll
  for (int t = 0; t < 5; ++t) bnd[t] = sub[b0 + t];   // d=NN-1,half=1: sub[NN*8]=EE valid
#pragma unroll
  for (int r = 0; r < 4; ++r) {
    int s = bnd[r], e = bnd[r + 1];
    float a0 = 0.f, a1 = 0.f, a2 = 0.f, a3 = 0.f;
    int i = s;
    for (; i + 1 < e; i += 2) {
      int s0 = eidx[i], s1 = eidx[i + 1];
      ushort4 v0 = *(const ushort4*)(Xb + (size_t)s0 * 256 + o4);
      ushort4 v1 = *(const ushort4*)(Xb + (size_t)s1 * 256 + o4);
      a0 += bf2f(v0.x) + bf2f(v1.x);
      a1 += bf2f(v0.y) + bf2f(v1.y);
      a2 += bf2f(v0.z) + bf2f(v1.z);
      a3 += bf2f(v0.w) + bf2f(v1.w);
    }
    if (i < e) {
      ushort4 v = *(const ushort4*)(Xb + (size_t)eidx[i] * 256 + o4);
      a0 += bf2f(v.x); a1 += bf2f(v.y); a2 += bf2f(v.z); a3 += bf2f(v.w);
    }
    ushort4 o;
    o.x = f2bf(a0); o.y = f2bf(a1); o.z = f2bf(a2); o.w = f2bf(a3);
    *(ushort4*)(gp + (half * 4 + r) * 256) = o;
  }
  if (half) *(ushort4*)(gp + 2048) = *(const ushort4*)(Xb + (size_t)d * 256 + o4);
}

// ---- fused GEMM + bias + LeakyReLU + LayerNorm: out = LN(leaky(G @ Wcat + bias))
// BM=64 (grid 782 ~ 3 blocks/CU), BN=256, BK=64; 512 thr = 8 waves (2M x 4N), wave tile 32x64.
// T2 swizzle: linear LDS dest + inverse-swizzled global SOURCE col + swizzled READ col.
__global__ __launch_bounds__(512) void gemm_fused_kernel(
    const unsigned short* __restrict__ G, const unsigned short* __restrict__ Bt,
    const float* __restrict__ bias, const float* __restrict__ gamma,
    const float* __restrict__ beta, float* __restrict__ out) {
  __shared__ __align__(16) unsigned short As[64 * 64];    // 8KB
  __shared__ __align__(16) unsigned short Bs[256 * 64];   // 32KB
  __shared__ float psum[64][4], psq[64][4];
  __shared__ float smu[64], sinv[64];
  const int tid = threadIdx.x, lane = tid & 63, wave = tid >> 6;
  const int wm = wave >> 2, wn = wave & 3;
  const int m0 = blockIdx.x * 64;

  f32x4 acc[2][4] = {};
  const int arow = tid >> 3;                              // 0..63
  const int keA  = ((tid & 7) ^ (arow & 7)) * 8;          // swizzled source col (bf16 elems)
  const unsigned int wbase = (unsigned int)((tid & ~63) * 16);  // wave-uniform LDS dest base

  for (int k0 = 0; k0 < KK; k0 += 64) {
    __builtin_amdgcn_global_load_lds(
        (const __attribute__((address_space(1))) unsigned int*)(G + (size_t)(m0 + arow) * KK + k0 + keA),
        (__attribute__((address_space(3))) unsigned int*)((char*)As + wbase), 16, 0, 0);
#pragma unroll
    for (int p = 0; p < 4; ++p)
      __builtin_amdgcn_global_load_lds(
          (const __attribute__((address_space(1))) unsigned int*)(Bt + (size_t)(p * 64 + arow) * KK + k0 + keA),
          (__attribute__((address_space(3))) unsigned int*)((char*)Bs + p * 8192 + wbase), 16, 0, 0);
    __syncthreads();

    const int rfr = lane & 15;
    const int ch  = lane >> 4;                            // 16B-chunk 0..3
#pragma unroll
    for (int kk = 0; kk < 2; ++kk) {
      short8 af[2], bfv[4];
#pragma unroll
      for (int m = 0; m < 2; ++m) {
        int row = wm * 32 + m * 16 + rfr;
        af[m] = *(const short8*)&As[row * 64 + (((kk * 4 + ch) ^ (row & 7)) * 8)];
      }
#pragma unroll
      for (int n = 0; n < 4; ++n) {
        int row = wn * 64 + n * 16 + rfr;
        bfv[n] = *(const short8*)&Bs[row * 64 + (((kk * 4 + ch) ^ (row & 7)) * 8)];
      }
#pragma unroll
      for (int m = 0; m < 2; ++m)
#pragma unroll
        for (int n = 0; n < 4; ++n)
          acc[m][n] = __builtin_amdgcn_mfma_f32_16x16x32_bf16(af[m], bfv[n], acc[m][n], 0, 0, 0);
    }
    __syncthreads();
  }

  // epilogue: +bias, leaky, per-row LN (row split across 4 wn-waves -> LDS partials)
  const int q = lane >> 4, c = lane & 15;
  int cols[4]; float bv[4], gv[4], bev[4];
#pragma unroll
  for (int n = 0; n < 4; ++n) {
    cols[n] = wn * 64 + n * 16 + c;
    bv[n] = bias[cols[n]]; gv[n] = gamma[cols[n]]; bev[n] = beta[cols[n]];
  }
#pragma unroll
  for (int m = 0; m < 2; ++m)
#pragma unroll
    for (int n = 0; n < 4; ++n)
#pragma unroll
      for (int j = 0; j < 4; ++j) {
        float h = acc[m][n][j] + bv[n];
        acc[m][n][j] = h > 0.f ? h : 0.1f * h;
      }
#pragma unroll
  for (int m = 0; m < 2; ++m)
#pragma unroll
    for (int j = 0; j < 4; ++j) {
      float s = 0.f, ss = 0.f;
#pragma unroll
      for (int n = 0; n < 4; ++n) { float h = acc[m][n][j]; s += h; ss += h * h; }
#pragma unroll
      for (int mask = 1; mask < 16; mask <<= 1) {
        s  += __shfl_xor(s, mask);
        ss += __shfl_xor(ss, mask);
      }
      int rl = wm * 32 + m * 16 + q * 4 + j;
      if (c == 0) { psum[rl][wn] = s; psq[rl][wn] = ss; }
    }
  __syncthreads();
  if (tid < 64) {
    float s  = psum[tid][0] + psum[tid][1] + psum[tid][2] + psum[tid][3];
    float ss = psq[tid][0] + psq[tid][1] + psq[tid][2] + psq[tid][3];
    float mu = s * (1.f / 256.f);
    float var = ss * (1.f / 256.f) - mu * mu;
    smu[tid] = mu; sinv[tid] = rsqrtf(var + 1e-5f);
  }
  __syncthreads();
#pragma unroll
  for (int m = 0; m < 2; ++m)
#pragma unroll
    for (int j = 0; j < 4; ++j) {
      int rl = wm * 32 + m * 16 + q * 4 + j;
      int gr = m0 + rl;
      if (gr < NN) {
        float mu = smu[rl], inv = sinv[rl];
#pragma unroll
        for (int n = 0; n < 4; ++n)
          out[(size_t)gr * 256 + cols[n]] = gv[n] * (acc[m][n][j] - mu) * inv + bev[n];
      }
    }
}

extern "C" void kernel_launch(void* const* d_in, const int* in_sizes, int n_in,
                              void* d_out, int out_size, void* d_ws, size_t ws_size,
                              hipStream_t stream) {
  const float* node_feats = (const float*)d_in[0];
  const int*   src        = (const int*)d_in[1];
  const int*   dst        = (const int*)d_in[2];
  const int*   etype      = (const int*)d_in[3];
  const float* bases      = (const float*)d_in[4];
  const float* comp       = (const float*)d_in[5];
  const float* loopw      = (const float*)d_in[6];
  const float* bias       = (const float*)d_in[7];
  const float* gamma      = (const float*)d_in[8];
  const float* beta       = (const float*)d_in[9];
  float* out = (float*)d_out;

  char* ws = (char*)d_ws;
  unsigned short* Xb   = (unsigned short*)(ws + OFF_XB);
  unsigned short* WT   = (unsigned short*)(ws + OFF_WT);
  unsigned short* G    = (unsigned short*)(ws + OFF_G);
  int*            cnt2 = (int*)(ws + OFF_CNT2);
  int*            offs = (int*)(ws + OFF_OFFS);
  int*            sub  = (int*)(ws + OFF_SUB);
  int*            eidx = (int*)(ws + OFF_EIX);

  build_w_kernel<<<dim3(9, 256), 256, 0, stream>>>(bases, comp, loopw, WT);
  convert_x_kernel<<<NN * 256 / 4 / 256, 256, 0, stream>>>(node_feats, Xb);

  hipMemsetAsync(cnt2, 0, NN * 8 * 4, stream);
  count_kernel<<<(EE + 255) / 256, 256, 0, stream>>>(dst, etype, cnt2);
  scan_kernel<<<1, 1024, 0, stream>>>(cnt2, offs);
  suboff_kernel<<<(NN + 255) / 256, 256, 0, stream>>>(cnt2, offs, sub);
  scatter_kernel<<<(EE + 255) / 256, 256, 0, stream>>>(src, dst, etype, sub, cnt2, eidx);

  gather_kernel<<<MP / 2, 256, 0, stream>>>(Xb, sub, eidx, G);
  gemm_fused_kernel<<<MP / 64, 512, 0, stream>>>(G, WT, bias, gamma, beta, out);
}

// Round 15
// 401.643 us; speedup vs baseline: 1.2322x; 1.2322x over previous
//
#include <hip/hip_runtime.h>

#define NN 50000
#define MP 50048        // 391*128 padded rows
#define EE 800000
#define KK 2304         // G cols = (R+1)*256; cols [2048,2304) = self features
#define NB 400000       // NN*8 (dst,rel) buckets
#define NSB 391         // ceil(NB/1024) scan blocks

typedef __attribute__((ext_vector_type(8))) short short8;
typedef __attribute__((ext_vector_type(4))) float f32x4;

__device__ __forceinline__ float bf2f(unsigned short u) {
  unsigned int x = ((unsigned int)u) << 16;
  float f; __builtin_memcpy(&f, &x, 4); return f;
}
__device__ __forceinline__ unsigned short f2bf(float f) {
  unsigned int x; __builtin_memcpy(&x, &f, 4);
  return (unsigned short)((x + 0x7fffu + ((x >> 16) & 1u)) >> 16);
}

// ws layout (bytes), 16B-aligned
constexpr size_t OFF_XB   = 0;                 // NN*256*2   = 25,600,000
constexpr size_t OFF_WT   = 25600000;          // 256*2304*2 =  1,179,648
constexpr size_t OFF_G    = 26779648;          // MP*2304*2  = 230,621,184 -> end 257,400,832
constexpr size_t OFF_CNT2 = 257400832;         // NB*4       =  1,600,000
constexpr size_t OFF_SUB  = 259000832;         // (NB+1)*4   =  1,600,004
constexpr size_t OFF_BSUM = 260600848;         // NSB*4
constexpr size_t OFF_EIX  = 260602416;         // EE*4 -> total ~263.8MB

// ---- build B^T bf16 [256 out-cols][2304 K]: Bt[o][r*256+i] = W_r[i][o]; cols 2048+: loop[i][o]
__global__ __launch_bounds__(256) void build_w_kernel(
    const float* __restrict__ bases, const float* __restrict__ comp,
    const float* __restrict__ loopw, unsigned short* __restrict__ Bt) {
  int kg = blockIdx.x * 256 + threadIdx.x;   // 0..2303 (gridDim.x = 9)
  int o  = blockIdx.y;                       // 0..255
  float v;
  if (kg < 2048) {
    int r = kg >> 8, i = kg & 255;
    v = 0.f;
#pragma unroll
    for (int b = 0; b < 4; ++b)
      v += comp[r * 4 + b] * bases[((size_t)b * 256 + i) * 256 + o];
  } else {
    v = loopw[(kg & 255) * 256 + o];
  }
  Bt[(size_t)o * KK + kg] = f2bf(v);
}

// ---- convert X fp32 -> bf16 (NN rows)
__global__ __launch_bounds__(256) void convert_x_kernel(
    const float* __restrict__ X, unsigned short* __restrict__ Xb) {
  size_t e0 = ((size_t)blockIdx.x * 256 + threadIdx.x) * 4;
  float4 v = *(const float4*)(X + e0);
  ushort4 o;
  o.x = f2bf(v.x); o.y = f2bf(v.y); o.z = f2bf(v.z); o.w = f2bf(v.w);
  *(ushort4*)(Xb + e0) = o;
}

// ---- CSR over (dst, rel) buckets
__global__ __launch_bounds__(256) void count_kernel(const int* __restrict__ dst,
                                                    const int* __restrict__ etype,
                                                    int* __restrict__ cnt2) {
  int e = blockIdx.x * 256 + threadIdx.x;
  if (e < EE) atomicAdd(&cnt2[dst[e] * 8 + etype[e]], 1);
}

// ---- parallel exclusive scan of cnt2[NB] -> sub[NB] (3 kernels)
__global__ __launch_bounds__(1024) void scan1_kernel(const int* __restrict__ cnt2,
                                                     int* __restrict__ sub,
                                                     int* __restrict__ bsum) {
  __shared__ int ws[16];
  int tid = threadIdx.x, lane = tid & 63, wid = tid >> 6;
  int i = blockIdx.x * 1024 + tid;
  int v = (i < NB) ? cnt2[i] : 0;
  int incl = v;
#pragma unroll
  for (int d = 1; d < 64; d <<= 1) {
    int t = __shfl_up(incl, d, 64);
    if (lane >= d) incl += t;
  }
  if (lane == 63) ws[wid] = incl;
  __syncthreads();
  int wpre = 0;
  for (int w = 0; w < wid; ++w) wpre += ws[w];
  if (i < NB) sub[i] = wpre + incl - v;      // block-local exclusive
  if (tid == 1023) bsum[blockIdx.x] = wpre + incl;
}

__global__ __launch_bounds__(512) void scan2_kernel(int* __restrict__ bsum) {
  __shared__ int ws[8];
  int tid = threadIdx.x, lane = tid & 63, wid = tid >> 6;
  int v = (tid < NSB) ? bsum[tid] : 0;
  int incl = v;
#pragma unroll
  for (int d = 1; d < 64; d <<= 1) {
    int t = __shfl_up(incl, d, 64);
    if (lane >= d) incl += t;
  }
  if (lane == 63) ws[wid] = incl;
  __syncthreads();
  int wpre = 0;
  for (int w = 0; w < wid; ++w) wpre += ws[w];
  if (tid < NSB) bsum[tid] = wpre + incl - v;  // exclusive (same-slot RW, no hazard)
}

__global__ __launch_bounds__(1024) void scan3_kernel(int* __restrict__ sub,
                                                     const int* __restrict__ bsum) {
  int i = blockIdx.x * 1024 + threadIdx.x;
  if (i < NB) sub[i] += bsum[blockIdx.x];
  if (i == 0) sub[NB] = EE;
}

// scatter src ids; cnt2 doubles as a decrementing cursor
__global__ __launch_bounds__(256) void scatter_kernel(
    const int* __restrict__ src, const int* __restrict__ dst,
    const int* __restrict__ etype, const int* __restrict__ sub,
    int* __restrict__ cnt2, int* __restrict__ eidx) {
  int e = blockIdx.x * 256 + threadIdx.x;
  if (e < EE) {
    int b = dst[e] * 8 + etype[e];
    int pos = atomicAdd(&cnt2[b], -1) - 1;
    eidx[sub[b] + pos] = src[e];
  }
}

// ---- gather-sum: G[d][r*256+i] = sum_{e in seg(d,r)} x[src][i]; G[d][2048+i] = x[d][i]
// TWO waves per node (half=0: r0..3, half=1: r4..7 + self)
__global__ __launch_bounds__(256) void gather_kernel(
    const unsigned short* __restrict__ Xb, const int* __restrict__ sub,
    const int* __restrict__ eidx, unsigned short* __restrict__ G) {
  int wid = threadIdx.x >> 6, lane = threadIdx.x & 63;
  int d = blockIdx.x * 2 + (wid >> 1);     // grid 25024*2 = 50048 = MP
  int half = wid & 1;
  int o4 = lane * 4;
  unsigned short* gp = G + (size_t)d * KK + o4;
  if (d >= NN) {                           // zero pad rows (GEMM-safe)
    ushort4 z = {0, 0, 0, 0};
    if (half == 0) {
#pragma unroll
      for (int r = 0; r < 4; ++r) *(ushort4*)(gp + r * 256) = z;
    } else {
#pragma unroll
      for (int r = 4; r < 9; ++r) *(ushort4*)(gp + r * 256) = z;
    }
    return;
  }
  const int b0 = d * 8 + half * 4;
  int bnd[5];
#pragma unroll
  for (int t = 0; t < 5; ++t) bnd[t] = sub[b0 + t];   // sub[NB]=EE valid for d=NN-1,half=1
#pragma unroll
  for (int r = 0; r < 4; ++r) {
    int s = bnd[r], e = bnd[r + 1];
    float a0 = 0.f, a1 = 0.f, a2 = 0.f, a3 = 0.f;
    int i = s;
    for (; i + 1 < e; i += 2) {
      int s0 = eidx[i], s1 = eidx[i + 1];
      ushort4 v0 = *(const ushort4*)(Xb + (size_t)s0 * 256 + o4);
      ushort4 v1 = *(const ushort4*)(Xb + (size_t)s1 * 256 + o4);
      a0 += bf2f(v0.x) + bf2f(v1.x);
      a1 += bf2f(v0.y) + bf2f(v1.y);
      a2 += bf2f(v0.z) + bf2f(v1.z);
      a3 += bf2f(v0.w) + bf2f(v1.w);
    }
    if (i < e) {
      ushort4 v = *(const ushort4*)(Xb + (size_t)eidx[i] * 256 + o4);
      a0 += bf2f(v.x); a1 += bf2f(v.y); a2 += bf2f(v.z); a3 += bf2f(v.w);
    }
    ushort4 o;
    o.x = f2bf(a0); o.y = f2bf(a1); o.z = f2bf(a2); o.w = f2bf(a3);
    *(ushort4*)(gp + (half * 4 + r) * 256) = o;
  }
  if (half) *(ushort4*)(gp + 2048) = *(const ushort4*)(Xb + (size_t)d * 256 + o4);
}

// ---- fused GEMM + bias + LeakyReLU + LayerNorm (round-10 measured-best config)
// BM=128, BN=256, BK=64; 512 thr = 8 waves (2M x 4N), wave tile 64x64. T2 swizzle.
__global__ __launch_bounds__(512) void gemm_fused_kernel(
    const unsigned short* __restrict__ G, const unsigned short* __restrict__ Bt,
    const float* __restrict__ bias, const float* __restrict__ gamma,
    const float* __restrict__ beta, float* __restrict__ out) {
  __shared__ __align__(16) unsigned short As[128 * 64];   // 16KB
  __shared__ __align__(16) unsigned short Bs[256 * 64];   // 32KB
  __shared__ float psum[128][4], psq[128][4];
  __shared__ float smu[128], sinv[128];
  const int tid = threadIdx.x, lane = tid & 63, wave = tid >> 6;
  const int wm = wave >> 2, wn = wave & 3;
  const int m0 = blockIdx.x * 128;

  f32x4 acc[4][4] = {};
  const int arow = tid >> 3;                              // 0..63
  const int keA  = ((tid & 7) ^ (arow & 7)) * 8;          // swizzled source col (bf16 elems)
  const unsigned int wbase = (unsigned int)((tid & ~63) * 16);  // wave-uniform LDS dest base

  for (int k0 = 0; k0 < KK; k0 += 64) {
    __builtin_amdgcn_global_load_lds(
        (const __attribute__((address_space(1))) unsigned int*)(G + (size_t)(m0 + arow) * KK + k0 + keA),
        (__attribute__((address_space(3))) unsigned int*)((char*)As + wbase), 16, 0, 0);
    __builtin_amdgcn_global_load_lds(
        (const __attribute__((address_space(1))) unsigned int*)(G + (size_t)(m0 + 64 + arow) * KK + k0 + keA),
        (__attribute__((address_space(3))) unsigned int*)((char*)As + 8192 + wbase), 16, 0, 0);
#pragma unroll
    for (int p = 0; p < 4; ++p)
      __builtin_amdgcn_global_load_lds(
          (const __attribute__((address_space(1))) unsigned int*)(Bt + (size_t)(p * 64 + arow) * KK + k0 + keA),
          (__attribute__((address_space(3))) unsigned int*)((char*)Bs + p * 8192 + wbase), 16, 0, 0);
    __syncthreads();

    const int rfr = lane & 15;
    const int ch  = lane >> 4;                            // 16B-chunk 0..3
#pragma unroll
    for (int kk = 0; kk < 2; ++kk) {
      short8 af[4], bfv[4];
#pragma unroll
      for (int m = 0; m < 4; ++m) {
        int row = wm * 64 + m * 16 + rfr;
        af[m] = *(const short8*)&As[row * 64 + (((kk * 4 + ch) ^ (row & 7)) * 8)];
      }
#pragma unroll
      for (int n = 0; n < 4; ++n) {
        int row = wn * 64 + n * 16 + rfr;
        bfv[n] = *(const short8*)&Bs[row * 64 + (((kk * 4 + ch) ^ (row & 7)) * 8)];
      }
#pragma unroll
      for (int m = 0; m < 4; ++m)
#pragma unroll
        for (int n = 0; n < 4; ++n)
          acc[m][n] = __builtin_amdgcn_mfma_f32_16x16x32_bf16(af[m], bfv[n], acc[m][n], 0, 0, 0);
    }
    __syncthreads();
  }

  // epilogue: +bias, leaky, per-row LN (row split across 4 wn-waves -> LDS partials)
  const int q = lane >> 4, c = lane & 15;
  int cols[4]; float bv[4], gv[4], bev[4];
#pragma unroll
  for (int n = 0; n < 4; ++n) {
    cols[n] = wn * 64 + n * 16 + c;
    bv[n] = bias[cols[n]]; gv[n] = gamma[cols[n]]; bev[n] = beta[cols[n]];
  }
#pragma unroll
  for (int m = 0; m < 4; ++m)
#pragma unroll
    for (int n = 0; n < 4; ++n)
#pragma unroll
      for (int j = 0; j < 4; ++j) {
        float h = acc[m][n][j] + bv[n];
        acc[m][n][j] = h > 0.f ? h : 0.1f * h;
      }
#pragma unroll
  for (int m = 0; m < 4; ++m)
#pragma unroll
    for (int j = 0; j < 4; ++j) {
      float s = 0.f, ss = 0.f;
#pragma unroll
      for (int n = 0; n < 4; ++n) { float h = acc[m][n][j]; s += h; ss += h * h; }
#pragma unroll
      for (int mask = 1; mask < 16; mask <<= 1) {
        s  += __shfl_xor(s, mask);
        ss += __shfl_xor(ss, mask);
      }
      int rl = wm * 64 + m * 16 + q * 4 + j;
      if (c == 0) { psum[rl][wn] = s; psq[rl][wn] = ss; }
    }
  __syncthreads();
  if (tid < 128) {
    float s  = psum[tid][0] + psum[tid][1] + psum[tid][2] + psum[tid][3];
    float ss = psq[tid][0] + psq[tid][1] + psq[tid][2] + psq[tid][3];
    float mu = s * (1.f / 256.f);
    float var = ss * (1.f / 256.f) - mu * mu;
    smu[tid] = mu; sinv[tid] = rsqrtf(var + 1e-5f);
  }
  __syncthreads();
#pragma unroll
  for (int m = 0; m < 4; ++m)
#pragma unroll
    for (int j = 0; j < 4; ++j) {
      int rl = wm * 64 + m * 16 + q * 4 + j;
      int gr = m0 + rl;
      if (gr < NN) {
        float mu = smu[rl], inv = sinv[rl];
#pragma unroll
        for (int n = 0; n < 4; ++n)
          out[(size_t)gr * 256 + cols[n]] = gv[n] * (acc[m][n][j] - mu) * inv + bev[n];
      }
    }
}

extern "C" void kernel_launch(void* const* d_in, const int* in_sizes, int n_in,
                              void* d_out, int out_size, void* d_ws, size_t ws_size,
                              hipStream_t stream) {
  const float* node_feats = (const float*)d_in[0];
  const int*   src        = (const int*)d_in[1];
  const int*   dst        = (const int*)d_in[2];
  const int*   etype      = (const int*)d_in[3];
  const float* bases      = (const float*)d_in[4];
  const float* comp       = (const float*)d_in[5];
  const float* loopw      = (const float*)d_in[6];
  const float* bias       = (const float*)d_in[7];
  const float* gamma      = (const float*)d_in[8];
  const float* beta       = (const float*)d_in[9];
  float* out = (float*)d_out;

  char* ws = (char*)d_ws;
  unsigned short* Xb   = (unsigned short*)(ws + OFF_XB);
  unsigned short* WT   = (unsigned short*)(ws + OFF_WT);
  unsigned short* G    = (unsigned short*)(ws + OFF_G);
  int*            cnt2 = (int*)(ws + OFF_CNT2);
  int*            sub  = (int*)(ws + OFF_SUB);
  int*            bsum = (int*)(ws + OFF_BSUM);
  int*            eidx = (int*)(ws + OFF_EIX);

  build_w_kernel<<<dim3(9, 256), 256, 0, stream>>>(bases, comp, loopw, WT);
  convert_x_kernel<<<NN * 256 / 4 / 256, 256, 0, stream>>>(node_feats, Xb);

  hipMemsetAsync(cnt2, 0, NB * 4, stream);
  count_kernel<<<(EE + 255) / 256, 256, 0, stream>>>(dst, etype, cnt2);
  scan1_kernel<<<NSB, 1024, 0, stream>>>(cnt2, sub, bsum);
  scan2_kernel<<<1, 512, 0, stream>>>(bsum);
  scan3_kernel<<<NSB, 1024, 0, stream>>>(sub, bsum);
  scatter_kernel<<<(EE + 255) / 256, 256, 0, stream>>>(src, dst, etype, sub, cnt2, eidx);

  gather_kernel<<<MP / 2, 256, 0, stream>>>(Xb, sub, eidx, G);
  gemm_fused_kernel<<<MP / 128, 512, 0, stream>>>(G, WT, bias, gamma, beta, out);
}